// Round 3
// baseline (245.177 us; speedup 1.0000x reference)
//
#include <hip/hip_runtime.h>

#define BB 4
#define PP 8
#define NN 4096
#define EE 65536
#define SLOTS 48   // Poisson(16) degree; P(deg>=48) ~ 1e-11 -> safe, clamped anyway

// ---------------- workspace layout (bytes) ----------------
// h      : [B*P][N][64] f32 @ 0          (33,554,432)
// deg    : [B][N] int       @ 33554432   (65,536)
// cursor : [B][N] int       @ 33619968   (65,536)   <- deg+cursor zeroed by one memset
// dinv   : [B][N] f32       @ 33685504   (65,536)
// bucket : [B][N][48] int2  @ 33751040   (6,291,456)
// total ~ 40.0 MB
#define OFF_DEG    33554432u
#define OFF_CUR    33619968u
#define OFF_DINV   33685504u
#define OFF_BUCKET 33751040u

// ---------------- degree histogram over dst ----------------
__global__ void k_hist(const int* __restrict__ ei, int* __restrict__ deg) {
    const int idx = blockIdx.x * 256 + threadIdx.x;  // 0 .. B*E
    const int b = idx >> 16;
    const int e = idx & (EE - 1);
    const int d = ei[((size_t)b * 2 + 1) * EE + e];
    atomicAdd(&deg[b * NN + d], 1);
}

// ---------------- dinv = rsqrt(deg+1) ----------------
__global__ void k_dinv(const int* __restrict__ deg, float* __restrict__ dinv) {
    const int i = blockIdx.x * 256 + threadIdx.x;  // 0 .. B*N
    dinv[i] = rsqrtf((float)(deg[i] + 1));
}

// ---------------- bucket fill: (src, dinv[src]) per dst slot ----------------
__global__ void k_bucket(const int* __restrict__ ei, int* __restrict__ cursor,
                         const float* __restrict__ dinv, int2* __restrict__ bucket) {
    const int idx = blockIdx.x * 256 + threadIdx.x;
    const int b = idx >> 16;
    const int e = idx & (EE - 1);
    const int s = ei[(size_t)b * 2 * EE + e];
    const int d = ei[(size_t)b * 2 * EE + EE + e];
    const int pos = atomicAdd(&cursor[b * NN + d], 1);
    if (pos < SLOTS) {
        int2 v;
        v.x = s;
        v.y = __float_as_int(dinv[b * NN + s]);
        bucket[(size_t)(b * NN + d) * SLOTS + pos] = v;
    }
}

// ---------------- GEMM: h[row][c] = sum_k x[row][k] * W[k][c] ----------------
// One wave per 32 rows; lane = output channel. W column in 64 VGPRs; the x row
// is wave-uniform -> scalar loads (s_load_dwordx4) feeding v_fma SGPR operands.
__global__ __launch_bounds__(256) void k_gemm(const float* __restrict__ x,
                                              const float* __restrict__ W,
                                              float* __restrict__ h) {
    const int lane = threadIdx.x & 63;
    const int wv   = threadIdx.x >> 6;
    float wreg[64];
#pragma unroll
    for (int k = 0; k < 64; ++k) wreg[k] = W[k * 64 + lane];

    const int wid = blockIdx.x * 4 + wv;  // 0..4095, 32 rows each
    const float4* xr = (const float4*)(x + (size_t)wid * 32 * 64);
    float* hr = h + (size_t)wid * 32 * 64;

    for (int r = 0; r < 32; ++r) {
        float a0 = 0.f, a1 = 0.f, a2 = 0.f, a3 = 0.f;
#pragma unroll
        for (int k4 = 0; k4 < 16; k4 += 4) {
            float4 v0 = xr[r * 16 + k4 + 0];
            float4 v1 = xr[r * 16 + k4 + 1];
            float4 v2 = xr[r * 16 + k4 + 2];
            float4 v3 = xr[r * 16 + k4 + 3];
            a0 = fmaf(v0.x, wreg[4 * k4 + 0], a0);
            a0 = fmaf(v0.y, wreg[4 * k4 + 1], a0);
            a0 = fmaf(v0.z, wreg[4 * k4 + 2], a0);
            a0 = fmaf(v0.w, wreg[4 * k4 + 3], a0);
            a1 = fmaf(v1.x, wreg[4 * k4 + 4], a1);
            a1 = fmaf(v1.y, wreg[4 * k4 + 5], a1);
            a1 = fmaf(v1.z, wreg[4 * k4 + 6], a1);
            a1 = fmaf(v1.w, wreg[4 * k4 + 7], a1);
            a2 = fmaf(v2.x, wreg[4 * k4 + 8], a2);
            a2 = fmaf(v2.y, wreg[4 * k4 + 9], a2);
            a2 = fmaf(v2.z, wreg[4 * k4 + 10], a2);
            a2 = fmaf(v2.w, wreg[4 * k4 + 11], a2);
            a3 = fmaf(v3.x, wreg[4 * k4 + 12], a3);
            a3 = fmaf(v3.y, wreg[4 * k4 + 13], a3);
            a3 = fmaf(v3.z, wreg[4 * k4 + 14], a3);
            a3 = fmaf(v3.w, wreg[4 * k4 + 15], a3);
        }
        hr[r * 64 + lane] = (a0 + a1) + (a2 + a3);
    }
}

// ---------------- aggregation + bias + PReLU, XCD-partitioned frame pairs ----
// One wave per (frame-pair, node). XCD x owns frames [4x, 4x+4): each h frame
// is fetched into exactly one XCD's L2 once; working set 2 MB < 4 MiB L2.
// acc_f = dinv[i]*h_f[i] + sum_e dinv[src]*h_f[src]; out = prelu(di*acc + b).
__global__ __launch_bounds__(256) void k_agg(const float* __restrict__ h,
                                             const int* __restrict__ deg,
                                             const float* __restrict__ dinv,
                                             const int2* __restrict__ bucket,
                                             const float* __restrict__ bias,
                                             const float* __restrict__ pa,
                                             float* __restrict__ out) {
    const int lane = threadIdx.x & 63;
    const int wv   = threadIdx.x >> 6;
    const int g    = blockIdx.x;          // 16384 blocks
    const int xcd  = g & 7;
    const int idx  = g >> 3;              // 0..2047
    const int pair = xcd * 2 + (idx >> 10);  // 0..15
    const int bp0  = pair * 2;               // frames bp0, bp0+1
    const int b    = bp0 >> 3;
    const int i    = ((idx & 1023) << 2) + wv;

    const int   nd = min(deg[b * NN + i], SLOTS);
    const float di = dinv[b * NN + i];
    const int2* bk = bucket + (size_t)(b * NN + i) * SLOTS;
    const float* h0 = h + ((size_t)bp0 << 18);   // frame bp0
    const float* h1 = h0 + (1u << 18);           // frame bp0+1

    const int self = (i << 6) + lane;            // 32-bit voffset (< 1 MB)
    float acc0 = di * h0[self];
    float acc1 = di * h1[self];
    float c0 = 0.f, c1 = 0.f;

    int e = 0;
    for (; e + 2 <= nd; e += 2) {
        const int2 e0 = bk[e];
        const int2 e1 = bk[e + 1];
        const int o0 = (e0.x << 6) + lane;
        const int o1 = (e1.x << 6) + lane;
        const float w0 = __int_as_float(e0.y);
        const float w1 = __int_as_float(e1.y);
        acc0 = fmaf(w0, h0[o0], acc0);
        acc1 = fmaf(w0, h1[o0], acc1);
        c0   = fmaf(w1, h0[o1], c0);
        c1   = fmaf(w1, h1[o1], c1);
    }
    if (e < nd) {
        const int2 e0 = bk[e];
        const int o0 = (e0.x << 6) + lane;
        const float w0 = __int_as_float(e0.y);
        acc0 = fmaf(w0, h0[o0], acc0);
        acc1 = fmaf(w0, h1[o0], acc1);
    }
    acc0 += c0;
    acc1 += c1;

    const float bs = bias[lane];
    const float a  = pa[0];
    float r0 = fmaf(di, acc0, bs);
    float r1 = fmaf(di, acc1, bs);
    r0 = r0 >= 0.f ? r0 : a * r0;
    r1 = r1 >= 0.f ? r1 : a * r1;
    out[((size_t)bp0 * NN + i) * 64 + lane] = r0;
    out[((size_t)(bp0 + 1) * NN + i) * 64 + lane] = r1;
}

extern "C" void kernel_launch(void* const* d_in, const int* in_sizes, int n_in,
                              void* d_out, int out_size, void* d_ws, size_t ws_size,
                              hipStream_t stream) {
    const float* x    = (const float*)d_in[0];
    const int*   ei   = (const int*)d_in[1];
    const float* W    = (const float*)d_in[2];
    const float* bias = (const float*)d_in[3];
    const float* pa   = (const float*)d_in[4];
    float* out = (float*)d_out;

    char* ws = (char*)d_ws;
    float* h      = (float*)ws;
    int*   deg    = (int*)(ws + OFF_DEG);
    int*   cur    = (int*)(ws + OFF_CUR);
    float* dinv   = (float*)(ws + OFF_DINV);
    int2*  bucket = (int2*)(ws + OFF_BUCKET);

    // zero deg + cursor (contiguous 128 KB); ws is re-poisoned before every call
    hipMemsetAsync(deg, 0, 2 * BB * NN * sizeof(int), stream);

    k_hist<<<(BB * EE) / 256, 256, 0, stream>>>(ei, deg);
    k_dinv<<<(BB * NN) / 256, 256, 0, stream>>>(deg, dinv);
    k_bucket<<<(BB * EE) / 256, 256, 0, stream>>>(ei, cur, dinv, bucket);
    k_gemm<<<1024, 256, 0, stream>>>(x, W, h);
    k_agg<<<(BB * PP * NN) / 8, 256, 0, stream>>>(h, deg, dinv, bucket, bias, pa, out);
}

// Round 6
// 190.476 us; speedup vs baseline: 1.2872x; 1.2872x over previous
//
#include <hip/hip_runtime.h>

#define BB 4
#define PP 8
#define NN 4096
#define EE 65536
#define SLOTS 48   // Poisson(16) degree; P(deg>=48) ~ 1e-11 -> safe, clamped anyway

// ---------------- workspace layout (bytes) ----------------
// h      : [B*P][N][64] f32 @ 0          (33,554,432)
// deg    : [B][N] int       @ 33554432   (65,536)
// cursor : [B][N] int       @ 33619968   (65,536)   <- deg+cursor zeroed by one memset
// dinv   : [B][N] f32       @ 33685504   (65,536)
// bucket : [B][N][48] int   @ 33751040   (3,145,728)
// total ~ 36.9 MB
#define OFF_DEG    33554432u
#define OFF_CUR    33619968u
#define OFF_DINV   33685504u
#define OFF_BUCKET 33751040u

// ---------------- degree histogram over dst ----------------
__global__ void k_hist(const int* __restrict__ ei, int* __restrict__ deg) {
    const int idx = blockIdx.x * 256 + threadIdx.x;  // 0 .. B*E
    const int b = idx >> 16;
    const int e = idx & (EE - 1);
    const int d = ei[((size_t)b * 2 + 1) * EE + e];
    atomicAdd(&deg[b * NN + d], 1);
}

// ---------------- dinv = rsqrt(deg+1) ----------------
__global__ void k_dinv(const int* __restrict__ deg, float* __restrict__ dinv) {
    const int i = blockIdx.x * 256 + threadIdx.x;  // 0 .. B*N
    dinv[i] = rsqrtf((float)(deg[i] + 1));
}

// ---------------- bucket fill: src id per dst slot (4 B scattered writes) ----
__global__ void k_bucket(const int* __restrict__ ei, int* __restrict__ cursor,
                         int* __restrict__ bucket) {
    const int idx = blockIdx.x * 256 + threadIdx.x;
    const int b = idx >> 16;
    const int e = idx & (EE - 1);
    const int s = ei[(size_t)b * 2 * EE + e];
    const int d = ei[(size_t)b * 2 * EE + EE + e];
    const int pos = atomicAdd(&cursor[b * NN + d], 1);
    if (pos < SLOTS)
        bucket[(size_t)(b * NN + d) * SLOTS + pos] = s;
}

// ---------------- GEMM: h[row][c] = sum_k x[row][k] * W[k][c] ----------------
// 2048 blocks x 256 thr (32 waves/CU). Block stages 64 rows (16 KB) in LDS with
// ONE sync; W column in 64 VGPRs/lane; x rows come back as broadcast
// ds_read_b128 (uniform addr, conflict-free). 2 rows x 2 accs = 4 FMA chains.
__global__ __launch_bounds__(256) void k_gemm(const float* __restrict__ x,
                                              const float* __restrict__ W,
                                              float* __restrict__ h) {
    __shared__ __align__(16) float xl[64 * 64];
    const int lane = threadIdx.x & 63;
    const int wv   = threadIdx.x >> 6;

    float wreg[64];
#pragma unroll
    for (int k = 0; k < 64; ++k) wreg[k] = W[k * 64 + lane];

    const size_t base = (size_t)blockIdx.x * 64 * 64;  // 64 rows per block
    const float4* xg = (const float4*)(x + base);
    float4* xs = (float4*)xl;
#pragma unroll
    for (int j = 0; j < 4; ++j)
        xs[j * 256 + threadIdx.x] = xg[j * 256 + threadIdx.x];
    __syncthreads();

    float* hb = h + base;
#pragma unroll 1
    for (int r0 = wv * 16; r0 < wv * 16 + 16; r0 += 2) {
        const float4* xa = (const float4*)&xl[r0 * 64];
        const float4* xb = (const float4*)&xl[(r0 + 1) * 64];
        float a0 = 0.f, a1 = 0.f, b0 = 0.f, b1 = 0.f;
#pragma unroll
        for (int k4 = 0; k4 < 16; k4 += 2) {
            const float4 va0 = xa[k4], va1 = xa[k4 + 1];
            const float4 vb0 = xb[k4], vb1 = xb[k4 + 1];
            a0 = fmaf(va0.x, wreg[4 * k4 + 0], a0);
            a0 = fmaf(va0.y, wreg[4 * k4 + 1], a0);
            a0 = fmaf(va0.z, wreg[4 * k4 + 2], a0);
            a0 = fmaf(va0.w, wreg[4 * k4 + 3], a0);
            a1 = fmaf(va1.x, wreg[4 * k4 + 4], a1);
            a1 = fmaf(va1.y, wreg[4 * k4 + 5], a1);
            a1 = fmaf(va1.z, wreg[4 * k4 + 6], a1);
            a1 = fmaf(va1.w, wreg[4 * k4 + 7], a1);
            b0 = fmaf(vb0.x, wreg[4 * k4 + 0], b0);
            b0 = fmaf(vb0.y, wreg[4 * k4 + 1], b0);
            b0 = fmaf(vb0.z, wreg[4 * k4 + 2], b0);
            b0 = fmaf(vb0.w, wreg[4 * k4 + 3], b0);
            b1 = fmaf(vb1.x, wreg[4 * k4 + 4], b1);
            b1 = fmaf(vb1.y, wreg[4 * k4 + 5], b1);
            b1 = fmaf(vb1.z, wreg[4 * k4 + 6], b1);
            b1 = fmaf(vb1.w, wreg[4 * k4 + 7], b1);
        }
        hb[r0 * 64 + lane] = a0 + a1;
        hb[(r0 + 1) * 64 + lane] = b0 + b1;
    }
}

// ---------------- aggregation + bias + PReLU, XCD-partitioned frame pairs ----
// One wave per (frame-pair, node). XCD x owns frames [4x, 4x+4): each h frame
// is fetched into exactly one XCD's L2 once; working set 2 MB < 4 MiB L2.
// Edge weight dinv[src] comes from the per-batch 16 KB dinv table (L1-hit).
// acc_f = dinv[i]*h_f[i] + sum_e dinv[src]*h_f[src]; out = prelu(di*acc + b).
__global__ __launch_bounds__(256) void k_agg(const float* __restrict__ h,
                                             const int* __restrict__ deg,
                                             const float* __restrict__ dinv,
                                             const int* __restrict__ bucket,
                                             const float* __restrict__ bias,
                                             const float* __restrict__ pa,
                                             float* __restrict__ out) {
    const int lane = threadIdx.x & 63;
    const int wv   = threadIdx.x >> 6;
    const int g    = blockIdx.x;          // 16384 blocks
    const int xcd  = g & 7;
    const int idx  = g >> 3;              // 0..2047
    const int pair = xcd * 2 + (idx >> 10);  // 0..15
    const int bp0  = pair * 2;               // frames bp0, bp0+1
    const int b    = bp0 >> 3;
    const int i    = ((idx & 1023) << 2) + wv;

    const int   nd = min(deg[b * NN + i], SLOTS);
    const float di = dinv[b * NN + i];
    const int*  bk = bucket + (size_t)(b * NN + i) * SLOTS;
    const float* dv = dinv + b * NN;
    const float* h0 = h + ((size_t)bp0 << 18);   // frame bp0
    const float* h1 = h0 + (1u << 18);           // frame bp0+1

    const int self = (i << 6) + lane;            // 32-bit voffset (< 1 MB)
    float acc0 = di * h0[self];
    float acc1 = di * h1[self];
    float c0 = 0.f, c1 = 0.f;

    int e = 0;
    for (; e + 2 <= nd; e += 2) {
        const int2 jj = *(const int2*)(bk + e);  // row base is 192 B-aligned
        const float w0 = dv[jj.x];
        const float w1 = dv[jj.y];
        const int o0 = (jj.x << 6) + lane;
        const int o1 = (jj.y << 6) + lane;
        acc0 = fmaf(w0, h0[o0], acc0);
        acc1 = fmaf(w0, h1[o0], acc1);
        c0   = fmaf(w1, h0[o1], c0);
        c1   = fmaf(w1, h1[o1], c1);
    }
    if (e < nd) {
        const int j = bk[e];
        const float w = dv[j];
        const int o0 = (j << 6) + lane;
        acc0 = fmaf(w, h0[o0], acc0);
        acc1 = fmaf(w, h1[o0], acc1);
    }
    acc0 += c0;
    acc1 += c1;

    const float bs = bias[lane];
    const float a  = pa[0];
    float r0 = fmaf(di, acc0, bs);
    float r1 = fmaf(di, acc1, bs);
    r0 = r0 >= 0.f ? r0 : a * r0;
    r1 = r1 >= 0.f ? r1 : a * r1;
    out[((size_t)bp0 * NN + i) * 64 + lane] = r0;
    out[((size_t)(bp0 + 1) * NN + i) * 64 + lane] = r1;
}

extern "C" void kernel_launch(void* const* d_in, const int* in_sizes, int n_in,
                              void* d_out, int out_size, void* d_ws, size_t ws_size,
                              hipStream_t stream) {
    const float* x    = (const float*)d_in[0];
    const int*   ei   = (const int*)d_in[1];
    const float* W    = (const float*)d_in[2];
    const float* bias = (const float*)d_in[3];
    const float* pa   = (const float*)d_in[4];
    float* out = (float*)d_out;

    char* ws = (char*)d_ws;
    float* h      = (float*)ws;
    int*   deg    = (int*)(ws + OFF_DEG);
    int*   cur    = (int*)(ws + OFF_CUR);
    float* dinv   = (float*)(ws + OFF_DINV);
    int*   bucket = (int*)(ws + OFF_BUCKET);

    // zero deg + cursor (contiguous 128 KB); ws is re-poisoned before every call
    hipMemsetAsync(deg, 0, 2 * BB * NN * sizeof(int), stream);

    k_hist<<<(BB * EE) / 256, 256, 0, stream>>>(ei, deg);
    k_dinv<<<(BB * NN) / 256, 256, 0, stream>>>(deg, dinv);
    k_bucket<<<(BB * EE) / 256, 256, 0, stream>>>(ei, cur, bucket);
    k_gemm<<<(BB * PP * NN) / 64, 256, 0, stream>>>(x, W, h);
    k_agg<<<(BB * PP * NN) / 8, 256, 0, stream>>>(h, deg, dinv, bucket, bias, pa, out);
}

// Round 8
// 151.255 us; speedup vs baseline: 1.6210x; 1.2593x over previous
//
#include <hip/hip_runtime.h>

#define BB 4
#define PP 8
#define NN 4096
#define EE 65536
#define SLOTS 48   // Poisson(16) degree; P(deg>=48) ~ 1e-11 -> safe, clamped anyway

// ---------------- workspace layout (bytes) ----------------
// h      : [B*P][N][64] f32 @ 0          (33,554,432)
// deg    : [B][N] int       @ 33554432   (65,536)  cursor == final degree
// bucket : [B][N][48] int   @ 33619968   (3,145,728)
// total ~ 36.8 MB
#define OFF_DEG    33554432u
#define OFF_BUCKET 33619968u

// ---------------- fused: GEMM (blocks 0..2047) + bucket fill (2048..3071) ----
// GEMM: h[row][c] = sum_k x[row][k] * W[k][c]; 64 rows staged in LDS with one
// sync, W column in 64 VGPRs/lane, broadcast ds_read_b128, 4 FMA chains.
// Bucket: pos = atomicAdd(deg[b][dst]) ; bucket[b][dst][pos] = src. The cursor
// doubles as the degree table (k_hist eliminated).
__global__ __launch_bounds__(256) void k_fused(const float* __restrict__ x,
                                               const float* __restrict__ W,
                                               float* __restrict__ h,
                                               const int* __restrict__ ei,
                                               int* __restrict__ deg,
                                               int* __restrict__ bucket) {
    if (blockIdx.x < 2048) {
        // ---- GEMM part ----
        __shared__ __align__(16) float xl[64 * 64];
        const int lane = threadIdx.x & 63;
        const int wv   = threadIdx.x >> 6;

        float wreg[64];
#pragma unroll
        for (int k = 0; k < 64; ++k) wreg[k] = W[k * 64 + lane];

        const size_t base = (size_t)blockIdx.x * 64 * 64;  // 64 rows per block
        const float4* xg = (const float4*)(x + base);
        float4* xs = (float4*)xl;
#pragma unroll
        for (int j = 0; j < 4; ++j)
            xs[j * 256 + threadIdx.x] = xg[j * 256 + threadIdx.x];
        __syncthreads();

        float* hb = h + base;
#pragma unroll 1
        for (int r0 = wv * 16; r0 < wv * 16 + 16; r0 += 2) {
            const float4* xa = (const float4*)&xl[r0 * 64];
            const float4* xb = (const float4*)&xl[(r0 + 1) * 64];
            float a0 = 0.f, a1 = 0.f, b0 = 0.f, b1 = 0.f;
#pragma unroll
            for (int k4 = 0; k4 < 16; k4 += 2) {
                const float4 va0 = xa[k4], va1 = xa[k4 + 1];
                const float4 vb0 = xb[k4], vb1 = xb[k4 + 1];
                a0 = fmaf(va0.x, wreg[4 * k4 + 0], a0);
                a0 = fmaf(va0.y, wreg[4 * k4 + 1], a0);
                a0 = fmaf(va0.z, wreg[4 * k4 + 2], a0);
                a0 = fmaf(va0.w, wreg[4 * k4 + 3], a0);
                a1 = fmaf(va1.x, wreg[4 * k4 + 4], a1);
                a1 = fmaf(va1.y, wreg[4 * k4 + 5], a1);
                a1 = fmaf(va1.z, wreg[4 * k4 + 6], a1);
                a1 = fmaf(va1.w, wreg[4 * k4 + 7], a1);
                b0 = fmaf(vb0.x, wreg[4 * k4 + 0], b0);
                b0 = fmaf(vb0.y, wreg[4 * k4 + 1], b0);
                b0 = fmaf(vb0.z, wreg[4 * k4 + 2], b0);
                b0 = fmaf(vb0.w, wreg[4 * k4 + 3], b0);
                b1 = fmaf(vb1.x, wreg[4 * k4 + 4], b1);
                b1 = fmaf(vb1.y, wreg[4 * k4 + 5], b1);
                b1 = fmaf(vb1.z, wreg[4 * k4 + 6], b1);
                b1 = fmaf(vb1.w, wreg[4 * k4 + 7], b1);
            }
            hb[r0 * 64 + lane] = a0 + a1;
            hb[(r0 + 1) * 64 + lane] = b0 + b1;
        }
    } else {
        // ---- bucket-fill part ----
        const int idx = (blockIdx.x - 2048) * 256 + threadIdx.x;  // 0 .. B*E
        const int b = idx >> 16;
        const int e = idx & (EE - 1);
        const int s = ei[(size_t)b * 2 * EE + e];
        const int d = ei[(size_t)b * 2 * EE + EE + e];
        const int pos = atomicAdd(&deg[b * NN + d], 1);
        if (pos < SLOTS)
            bucket[(size_t)(b * NN + d) * SLOTS + pos] = s;
    }
}

// ---------------- aggregation + bias + PReLU, 4 frames/wave ------------------
// One wave per (frame-quad, node). XCD q owns frames [4q, 4q+4) (4 MB = L2):
// each h frame is fetched into exactly one XCD's L2 once. Per edge-pair iter:
// 8 independent h gathers into 8 accumulators (2x MLP vs frame-pair version).
// Edge weight rsqrtf(deg[src]+1) computed on the fly (deg table L1-resident).
__global__ __launch_bounds__(256) void k_agg(const float* __restrict__ h,
                                             const int* __restrict__ deg,
                                             const int* __restrict__ bucket,
                                             const float* __restrict__ bias,
                                             const float* __restrict__ pa,
                                             float* __restrict__ out) {
    const int lane = threadIdx.x & 63;
    const int wv   = threadIdx.x >> 6;
    const int g    = blockIdx.x;      // 8192 blocks
    const int q    = g & 7;           // XCD == frame quad
    const int idx  = g >> 3;          // 0..1023
    const int b    = q >> 1;
    const int i    = (idx << 2) + wv;

    const int* dgb = deg + b * NN;
    const int  ndr = dgb[i];
    const int  nd  = min(ndr, SLOTS);
    const float di = rsqrtf((float)(ndr + 1));
    const int* bk  = bucket + (size_t)(b * NN + i) * SLOTS;
    const float* h0 = h + ((size_t)(q * 4 + 0) << 18);
    const float* h1 = h + ((size_t)(q * 4 + 1) << 18);
    const float* h2 = h + ((size_t)(q * 4 + 2) << 18);
    const float* h3 = h + ((size_t)(q * 4 + 3) << 18);

    const int self = (i << 6) + lane;  // 32-bit voffset (< 1 MB per frame)
    float a0 = di * h0[self];
    float a1 = di * h1[self];
    float a2 = di * h2[self];
    float a3 = di * h3[self];
    float c0 = 0.f, c1 = 0.f, c2 = 0.f, c3 = 0.f;

    int e = 0;
    for (; e + 2 <= nd; e += 2) {
        const int2 jj = *(const int2*)(bk + e);  // row base is 192 B-aligned
        const int o0 = (jj.x << 6) + lane;
        const int o1 = (jj.y << 6) + lane;
        const float w0 = rsqrtf((float)(dgb[jj.x] + 1));
        const float w1 = rsqrtf((float)(dgb[jj.y] + 1));
        a0 = fmaf(w0, h0[o0], a0);
        a1 = fmaf(w0, h1[o0], a1);
        a2 = fmaf(w0, h2[o0], a2);
        a3 = fmaf(w0, h3[o0], a3);
        c0 = fmaf(w1, h0[o1], c0);
        c1 = fmaf(w1, h1[o1], c1);
        c2 = fmaf(w1, h2[o1], c2);
        c3 = fmaf(w1, h3[o1], c3);
    }
    if (e < nd) {
        const int j = bk[e];
        const int o = (j << 6) + lane;
        const float w = rsqrtf((float)(dgb[j] + 1));
        a0 = fmaf(w, h0[o], a0);
        a1 = fmaf(w, h1[o], a1);
        a2 = fmaf(w, h2[o], a2);
        a3 = fmaf(w, h3[o], a3);
    }
    a0 += c0; a1 += c1; a2 += c2; a3 += c3;

    const float bs = bias[lane];
    const float al = pa[0];
    float r0 = fmaf(di, a0, bs);
    float r1 = fmaf(di, a1, bs);
    float r2 = fmaf(di, a2, bs);
    float r3 = fmaf(di, a3, bs);
    r0 = r0 >= 0.f ? r0 : al * r0;
    r1 = r1 >= 0.f ? r1 : al * r1;
    r2 = r2 >= 0.f ? r2 : al * r2;
    r3 = r3 >= 0.f ? r3 : al * r3;
    out[((size_t)(q * 4 + 0) << 18) + self] = r0;
    out[((size_t)(q * 4 + 1) << 18) + self] = r1;
    out[((size_t)(q * 4 + 2) << 18) + self] = r2;
    out[((size_t)(q * 4 + 3) << 18) + self] = r3;
}

extern "C" void kernel_launch(void* const* d_in, const int* in_sizes, int n_in,
                              void* d_out, int out_size, void* d_ws, size_t ws_size,
                              hipStream_t stream) {
    const float* x    = (const float*)d_in[0];
    const int*   ei   = (const int*)d_in[1];
    const float* W    = (const float*)d_in[2];
    const float* bias = (const float*)d_in[3];
    const float* pa   = (const float*)d_in[4];
    float* out = (float*)d_out;

    char* ws = (char*)d_ws;
    float* h      = (float*)ws;
    int*   deg    = (int*)(ws + OFF_DEG);
    int*   bucket = (int*)(ws + OFF_BUCKET);

    // zero the degree/cursor table (64 KB); ws is re-poisoned before every call
    hipMemsetAsync(deg, 0, BB * NN * sizeof(int), stream);

    k_fused<<<3072, 256, 0, stream>>>(x, W, h, ei, deg, bucket);
    k_agg<<<(BB * PP * NN) / 16, 256, 0, stream>>>(h, deg, bucket, bias, pa, out);
}